// Round 10
// baseline (146.647 us; speedup 1.0000x reference)
//
#include <hip/hip_runtime.h>
#include <stdint.h>

// N=M=16384, D=64 fp32. dist[n,m] = a_sq[n] + b_sq[m] - 2 a.b; out = sum_n min_m.
// A(streamed) = TO pts in FRAGMENT order, B(resident) = -2*FROM.
// C[row=to][col=from]: min over rows is IN-LANE (tree16).
// R9 lesson: R7 (5 gather loads,10 MFMA) == R9 (8 coalesced,8 MFMA) == 49.5us
// -> not port-bound; the K-loop serializes load-wait-compute (vmcnt(0) stall
// ~250cyc/tile, no cross-iteration overlap). R10: manual 1-deep pipeline
// (t+=2 role swap, fits 128-reg cap now that rmin is 2 scalars), and the
// last-arriving block does the final reduction (finish kernel eliminated).
#define N_PTS 16384
#define TSPLITS 32
#define NBLOCKS (256 * TSPLITS / 4)  // 2048 blocks, 4 waves each
#define TO_TILES 16                  // per wave: 512 TO pts = 16 tiles of 32

typedef __attribute__((ext_vector_type(8)))  short bf16x8;
typedef __attribute__((ext_vector_type(16))) float f32x16;

__device__ __forceinline__ unsigned flipf(float f) {
    unsigned u = __float_as_uint(f);
    return u ^ (unsigned)((((int)u) >> 31) | (int)0x80000000);
}
__device__ __forceinline__ float unflipf(unsigned k) {
    unsigned u = (k & 0x80000000u) ? (k ^ 0x80000000u) : ~k;
    return __uint_as_float(u);
}
__device__ __forceinline__ unsigned short f2bf(float f) {
    unsigned u = __float_as_uint(f);
    u += 0x7FFFu + ((u >> 16) & 1u);   // RNE
    return (unsigned short)(u >> 16);
}
__device__ __forceinline__ float tree16(f32x16 a) {
    float m0 = fminf(fminf(a[0],  a[1]),  a[2]);
    float m1 = fminf(fminf(a[3],  a[4]),  a[5]);
    float m2 = fminf(fminf(a[6],  a[7]),  a[8]);
    float m3 = fminf(fminf(a[9],  a[10]), a[11]);
    float m4 = fminf(fminf(a[12], a[13]), a[14]);
    float m5 = fminf(fminf(a[15], m0), m1);
    return fminf(fminf(fminf(m2, m3), m4), m5);
}

// ---------- prep: fp32 -> bf16 FRAGMENT-ORDER operands + norms + init -----
__global__ __launch_bounds__(256) void prep_kernel(
        const float* __restrict__ from_pts, const float* __restrict__ to_pts,
        float* __restrict__ a_sq, float* __restrict__ bsqp,
        unsigned short* __restrict__ BfF, unsigned short* __restrict__ AtoF,
        unsigned* __restrict__ minkeys, unsigned* __restrict__ done) {
    int gid = blockIdx.x * 256 + threadIdx.x;   // 0 .. 524287
    int row = gid >> 3;                 // 0..32767 (FROM then TO)
    int sub = gid & 7;
    bool isFrom = row < N_PTS;
    int r = row & (N_PTS - 1);
    const float* src = isFrom ? from_pts : to_pts;
    float4 v0 = ((const float4*)src)[r * 16 + sub * 2];
    float4 v1 = ((const float4*)src)[r * 16 + sub * 2 + 1];
    float s = v0.x*v0.x + v0.y*v0.y + v0.z*v0.z + v0.w*v0.w
            + v1.x*v1.x + v1.y*v1.y + v1.z*v1.z + v1.w*v1.w;
    s += __shfl_xor(s, 1); s += __shfl_xor(s, 2); s += __shfl_xor(s, 4);
    float sc = isFrom ? -2.0f : 1.0f;
    union { unsigned short u[8]; uint4 q; } w;
    w.u[0] = f2bf(v0.x * sc); w.u[1] = f2bf(v0.y * sc);
    w.u[2] = f2bf(v0.z * sc); w.u[3] = f2bf(v0.w * sc);
    w.u[4] = f2bf(v1.x * sc); w.u[5] = f2bf(v1.y * sc);
    w.u[6] = f2bf(v1.z * sc); w.u[7] = f2bf(v1.w * sc);
    int st = r >> 5;                    // subtile / tile index (0..511)
    int m  = r & 31;
    int kb = sub >> 1, h = sub & 1;
    size_t fidx = (((size_t)st * 4 + kb) * 64 + h * 32 + m) * 8;
    if (isFrom) {
        *(uint4*)(BfF + fidx) = w.q;
        if (sub == 0) a_sq[r] = s;
    } else {
        *(uint4*)(AtoF + fidx) = w.q;
        // bsq in C/D-layout order: reg=(m&3)+4*(m>>3), h-half=(m>>2)&1
        if (sub == 0)
            bsqp[st * 32 + ((m >> 2) & 1) * 16 + (m & 3) + 4 * (m >> 3)] = s;
    }
    if (gid < N_PTS) minkeys[gid] = 0xFFFFFFFFu;
    if (gid == 0) *done = 0u;
}

// two sequential 4-MFMA chains (A-tile vs both resident B subtiles)
#define DO_TILE(A, CV)                                                          \
    {                                                                           \
        f32x16 acc0 = __builtin_amdgcn_mfma_f32_32x32x16_bf16(A[0], Bf0[0], CV, 0, 0, 0); \
        acc0 = __builtin_amdgcn_mfma_f32_32x32x16_bf16(A[1], Bf0[1], acc0, 0, 0, 0); \
        acc0 = __builtin_amdgcn_mfma_f32_32x32x16_bf16(A[2], Bf0[2], acc0, 0, 0, 0); \
        acc0 = __builtin_amdgcn_mfma_f32_32x32x16_bf16(A[3], Bf0[3], acc0, 0, 0, 0); \
        rmin0 = fminf(rmin0, tree16(acc0));                                     \
        f32x16 acc1 = __builtin_amdgcn_mfma_f32_32x32x16_bf16(A[0], Bf1[0], CV, 0, 0, 0); \
        acc1 = __builtin_amdgcn_mfma_f32_32x32x16_bf16(A[1], Bf1[1], acc1, 0, 0, 0); \
        acc1 = __builtin_amdgcn_mfma_f32_32x32x16_bf16(A[2], Bf1[2], acc1, 0, 0, 0); \
        acc1 = __builtin_amdgcn_mfma_f32_32x32x16_bf16(A[3], Bf1[3], acc1, 0, 0, 0); \
        rmin1 = fminf(rmin1, tree16(acc1));                                     \
    }

#define LOAD_TILE(GT, A, CV)                                                    \
    {                                                                           \
        const int gt_ = (GT);                                                   \
        A[0] = Av[((size_t)gt_ * 4 + 0) * 64 + lane];                           \
        A[1] = Av[((size_t)gt_ * 4 + 1) * 64 + lane];                           \
        A[2] = Av[((size_t)gt_ * 4 + 2) * 64 + lane];                           \
        A[3] = Av[((size_t)gt_ * 4 + 3) * 64 + lane];                           \
        const float4* cp_ = (const float4*)(bsqp + gt_ * 32 + h * 16);          \
        union { float4 f[4]; f32x16 v; } cu_;                                   \
        cu_.f[0] = cp_[0]; cu_.f[1] = cp_[1];                                   \
        cu_.f[2] = cp_[2]; cu_.f[3] = cp_[3];                                   \
        CV = cu_.v;                                                             \
    }

// ---------- main: pipelined MFMA + in-lane min; last block finishes -------
__global__ __launch_bounds__(256, 4) void main_kernel(
        const unsigned short* __restrict__ BfF,
        const unsigned short* __restrict__ AtoF,
        const float* __restrict__ bsqp, const float* __restrict__ a_sq,
        unsigned* __restrict__ minkeys, unsigned* __restrict__ done,
        float* __restrict__ out) {
    const int tid = threadIdx.x;
    const int lane = tid & 63;
    const int l31 = lane & 31;
    const int h   = lane >> 5;
    const int wid = (blockIdx.x << 2) + (tid >> 6);   // 0..8191
    const int fg  = wid & 255;          // 64 FROM pts per wave
    const int ts  = wid >> 8;           // 0..31; block's 4 waves: same ts

    const bf16x8* Bv = (const bf16x8*)BfF;
    const bf16x8* Av = (const bf16x8*)AtoF;

    // resident FROM fragments: subtiles 2*fg, 2*fg+1 (coalesced loads)
    bf16x8 Bf0[4], Bf1[4];
    #pragma unroll
    for (int kb = 0; kb < 4; kb++) {
        Bf0[kb] = Bv[((size_t)(2 * fg)     * 4 + kb) * 64 + lane];
        Bf1[kb] = Bv[((size_t)(2 * fg + 1) * 4 + kb) * 64 + lane];
    }

    float rmin0 = 3.0e38f, rmin1 = 3.0e38f;
    const int gtb = ts * TO_TILES;

    bf16x8 A0[4], A1[4];
    f32x16 c0v, c1v;
    LOAD_TILE(gtb, A0, c0v)
    #pragma unroll 1
    for (int t = 0; t < TO_TILES; t += 2) {
        LOAD_TILE(gtb + t + 1, A1, c1v)              // in flight over tile t
        DO_TILE(A0, c0v)
        LOAD_TILE(gtb + ((t + 2) & (TO_TILES - 1)), A0, c0v)  // over tile t+1
        DO_TILE(A1, c1v)
    }

    // cross-half min, then per-row device-scope atomicMin (flipped keys)
    rmin0 = fminf(rmin0, __shfl_xor(rmin0, 32));
    rmin1 = fminf(rmin1, __shfl_xor(rmin1, 32));
    if (lane < 32) {
        atomicMin(minkeys + fg * 64 + l31,      flipf(rmin0));
        atomicMin(minkeys + fg * 64 + 32 + l31, flipf(rmin1));
    }

    // ---- last-arriving block performs the final reduction ----
    __shared__ bool lastBlock;
    __shared__ float red[4];
    __syncthreads();                    // all waves' atomics issued
    if (tid == 0) {
        unsigned prev = __hip_atomic_fetch_add(done, 1u, __ATOMIC_ACQ_REL,
                                               __HIP_MEMORY_SCOPE_AGENT);
        lastBlock = (prev == NBLOCKS - 1);
        if (lastBlock)                  // one invalidate, not per-poll (R5!)
            __builtin_amdgcn_fence(__ATOMIC_ACQUIRE, "agent");
    }
    __syncthreads();
    if (!lastBlock) return;
    float s = 0.0f;
    for (int r = tid; r < N_PTS; r += 256)
        s += a_sq[r] + unflipf(minkeys[r]);
    #pragma unroll
    for (int k = 1; k < 64; k <<= 1) s += __shfl_xor(s, k);
    if ((tid & 63) == 0) red[tid >> 6] = s;
    __syncthreads();
    if (tid == 0) out[0] = red[0] + red[1] + red[2] + red[3];
}

extern "C" void kernel_launch(void* const* d_in, const int* in_sizes, int n_in,
                              void* d_out, int out_size, void* d_ws, size_t ws_size,
                              hipStream_t stream) {
    const float* from_pts = (const float*)d_in[0];
    const float* to_pts   = (const float*)d_in[1];
    char* ws = (char*)d_ws;
    float*          a_sq    = (float*)ws;                              //  64 KB
    float*          bsqp    = (float*)(ws + (64 << 10));               //  64 KB
    unsigned*       minkeys = (unsigned*)(ws + (128 << 10));           //  64 KB
    unsigned*       done    = (unsigned*)(ws + (192 << 10));           //  64 B
    unsigned short* BfF     = (unsigned short*)(ws + (256 << 10));               // 2 MB
    unsigned short* AtoF    = (unsigned short*)(ws + (256 << 10) + (2 << 20));   // 2 MB

    prep_kernel<<<(2 * N_PTS * 8) / 256, 256, 0, stream>>>(
        from_pts, to_pts, a_sq, bsqp, BfF, AtoF, minkeys, done);
    main_kernel<<<NBLOCKS, 256, 0, stream>>>(BfF, AtoF, bsqp, a_sq,
                                             minkeys, done, (float*)d_out);
}

// Round 11
// 92.602 us; speedup vs baseline: 1.5836x; 1.5836x over previous
//
#include <hip/hip_runtime.h>
#include <stdint.h>

// N=M=16384, D=64 fp32. dist[n,m] = a_sq[n] + b_sq[m] - 2 a.b; out = sum_n min_m.
// A(streamed) = TO pts in FRAGMENT order, B(resident) = -2*FROM.
// C[row=to][col=from]: min over rows is IN-LANE (tree16).
// R10 lesson: register prefetch + fused atomic epilogue BOTH regress (ACQ_REL
// RMW per block -> buffer_wbl2 storms; prefetch defeated by waitcnt). R11:
// the m97 mechanism instead -- global_load_lds DMA into double-buffered LDS,
// one 4KB A-tile staged per block per tile (4 waves x 1KB DMA), ds_read_b128
// fragments (block-broadcast), cinit staged in LDS. Epilogue reverted to
// R9's plain pmin stores + tiny finish kernel.
#define N_PTS 16384
#define TSPLITS 32
#define NBLOCKS (256 * TSPLITS / 4)  // 2048 blocks, 4 waves each
#define TO_TILES 16                  // per wave: 512 TO pts = 16 tiles of 32

typedef __attribute__((ext_vector_type(8)))  short bf16x8;
typedef __attribute__((ext_vector_type(16))) float f32x16;

__device__ __forceinline__ unsigned short f2bf(float f) {
    unsigned u = __float_as_uint(f);
    u += 0x7FFFu + ((u >> 16) & 1u);   // RNE
    return (unsigned short)(u >> 16);
}
__device__ __forceinline__ float tree16(f32x16 a) {
    float m0 = fminf(fminf(a[0],  a[1]),  a[2]);
    float m1 = fminf(fminf(a[3],  a[4]),  a[5]);
    float m2 = fminf(fminf(a[6],  a[7]),  a[8]);
    float m3 = fminf(fminf(a[9],  a[10]), a[11]);
    float m4 = fminf(fminf(a[12], a[13]), a[14]);
    float m5 = fminf(fminf(a[15], m0), m1);
    return fminf(fminf(fminf(m2, m3), m4), m5);
}

// ---------- prep: fp32 -> bf16 FRAGMENT-ORDER operands + norms ------------
__global__ __launch_bounds__(256) void prep_kernel(
        const float* __restrict__ from_pts, const float* __restrict__ to_pts,
        float* __restrict__ a_sq, float* __restrict__ bsqp,
        unsigned short* __restrict__ BfF, unsigned short* __restrict__ AtoF,
        float* __restrict__ out) {
    int gid = blockIdx.x * 256 + threadIdx.x;   // 0 .. 524287
    int row = gid >> 3;                 // 0..32767 (FROM then TO)
    int sub = gid & 7;
    bool isFrom = row < N_PTS;
    int r = row & (N_PTS - 1);
    const float* src = isFrom ? from_pts : to_pts;
    float4 v0 = ((const float4*)src)[r * 16 + sub * 2];
    float4 v1 = ((const float4*)src)[r * 16 + sub * 2 + 1];
    float s = v0.x*v0.x + v0.y*v0.y + v0.z*v0.z + v0.w*v0.w
            + v1.x*v1.x + v1.y*v1.y + v1.z*v1.z + v1.w*v1.w;
    s += __shfl_xor(s, 1); s += __shfl_xor(s, 2); s += __shfl_xor(s, 4);
    float sc = isFrom ? -2.0f : 1.0f;
    union { unsigned short u[8]; uint4 q; } w;
    w.u[0] = f2bf(v0.x * sc); w.u[1] = f2bf(v0.y * sc);
    w.u[2] = f2bf(v0.z * sc); w.u[3] = f2bf(v0.w * sc);
    w.u[4] = f2bf(v1.x * sc); w.u[5] = f2bf(v1.y * sc);
    w.u[6] = f2bf(v1.z * sc); w.u[7] = f2bf(v1.w * sc);
    int st = r >> 5;                    // subtile / tile index (0..511)
    int m  = r & 31;
    int kb = sub >> 1, h = sub & 1;
    size_t fidx = (((size_t)st * 4 + kb) * 64 + h * 32 + m) * 8;
    if (isFrom) {
        *(uint4*)(BfF + fidx) = w.q;
        if (sub == 0) a_sq[r] = s;
    } else {
        *(uint4*)(AtoF + fidx) = w.q;
        // bsq in C/D-layout order: reg=(m&3)+4*(m>>3), h-half=(m>>2)&1
        if (sub == 0)
            bsqp[st * 32 + ((m >> 2) & 1) * 16 + (m & 3) + 4 * (m >> 3)] = s;
    }
    if (gid == 0) out[0] = 0.0f;
}

// ---------- main: LDS-staged (global_load_lds) MFMA + in-lane min ---------
__global__ __launch_bounds__(256, 4) void main_kernel(
        const unsigned short* __restrict__ BfF,
        const unsigned short* __restrict__ AtoF,
        const float* __restrict__ bsqp, float* __restrict__ pmin) {
    // 2 x 4KB A-tile double buffer + 2KB cinit chunk
    __shared__ __align__(16) unsigned short abuf[2][2048];
    __shared__ __align__(16) float bsq_s[512];

    const int tid = threadIdx.x;
    const int lane = tid & 63;
    const int l31 = lane & 31;
    const int h   = lane >> 5;
    const int wv  = tid >> 6;           // wave 0..3
    const int wid = (blockIdx.x << 2) + wv;   // 0..8191
    const int fg  = wid & 255;          // 64 FROM pts per wave
    const int ts  = wid >> 8;           // 0..31; block's 4 waves share ts

    const bf16x8* Bv = (const bf16x8*)BfF;

    // stage this block's cinit chunk (512 floats, coalesced) into LDS
    bsq_s[tid]       = bsqp[ts * 512 + tid];
    bsq_s[tid + 256] = bsqp[ts * 512 + 256 + tid];

    // resident FROM fragments: subtiles 2*fg, 2*fg+1 (coalesced loads)
    bf16x8 Bf0[4], Bf1[4];
    #pragma unroll
    for (int kb = 0; kb < 4; kb++) {
        Bf0[kb] = Bv[((size_t)(2 * fg)     * 4 + kb) * 64 + lane];
        Bf1[kb] = Bv[((size_t)(2 * fg + 1) * 4 + kb) * 64 + lane];
    }

    const int gtb = ts * TO_TILES;
    // DMA one 1KB fragment-block per wave: lane-linear source, wave-uniform
    // LDS base + lane*16 (global_load_lds dst rule). 4 waves cover the tile.
    auto stage = [&](int gt, int buf) {
        const unsigned short* g = AtoF + (((size_t)gt * 4 + wv) * 64 + lane) * 8;
        unsigned short* l = &abuf[buf][wv * 512];
        __builtin_amdgcn_global_load_lds(
            (const __attribute__((address_space(1))) unsigned int*)g,
            (__attribute__((address_space(3))) unsigned int*)l, 16, 0, 0);
    };

    float rmin0 = 3.0e38f, rmin1 = 3.0e38f;
    auto compute = [&](int tl, int cb) {
        bf16x8 A[4];
        #pragma unroll
        for (int kb = 0; kb < 4; kb++)
            A[kb] = *(const bf16x8*)&abuf[cb][kb * 512 + lane * 8];
        union { float4 f[4]; f32x16 v; } cu;
        const float4* cp = (const float4*)&bsq_s[tl * 32 + h * 16];
        cu.f[0] = cp[0]; cu.f[1] = cp[1]; cu.f[2] = cp[2]; cu.f[3] = cp[3];
        f32x16 acc0 = __builtin_amdgcn_mfma_f32_32x32x16_bf16(A[0], Bf0[0], cu.v, 0, 0, 0);
        acc0 = __builtin_amdgcn_mfma_f32_32x32x16_bf16(A[1], Bf0[1], acc0, 0, 0, 0);
        acc0 = __builtin_amdgcn_mfma_f32_32x32x16_bf16(A[2], Bf0[2], acc0, 0, 0, 0);
        acc0 = __builtin_amdgcn_mfma_f32_32x32x16_bf16(A[3], Bf0[3], acc0, 0, 0, 0);
        rmin0 = fminf(rmin0, tree16(acc0));
        f32x16 acc1 = __builtin_amdgcn_mfma_f32_32x32x16_bf16(A[0], Bf1[0], cu.v, 0, 0, 0);
        acc1 = __builtin_amdgcn_mfma_f32_32x32x16_bf16(A[1], Bf1[1], acc1, 0, 0, 0);
        acc1 = __builtin_amdgcn_mfma_f32_32x32x16_bf16(A[2], Bf1[2], acc1, 0, 0, 0);
        acc1 = __builtin_amdgcn_mfma_f32_32x32x16_bf16(A[3], Bf1[3], acc1, 0, 0, 0);
        rmin1 = fminf(rmin1, tree16(acc1));
    };

    stage(gtb, 0);
    __syncthreads();                    // drains DMA0 + bsq_s ds_writes
    #pragma unroll 1
    for (int t = 0; t < TO_TILES - 1; t++) {
        stage(gtb + t + 1, (t + 1) & 1);   // DMA flies over this tile's MFMAs
        compute(t, t & 1);
        __syncthreads();                   // vmcnt drain: DMA t+1 landed; all
    }                                      // waves done reading buf t&1
    compute(TO_TILES - 1, (TO_TILES - 1) & 1);

    // cross-half min, then plain store: (ts,fg) is wave-unique -> no atomics
    rmin0 = fminf(rmin0, __shfl_xor(rmin0, 32));
    rmin1 = fminf(rmin1, __shfl_xor(rmin1, 32));
    if (lane < 32) {
        pmin[(size_t)ts * N_PTS + fg * 64 + l31]      = rmin0;
        pmin[(size_t)ts * N_PTS + fg * 64 + 32 + l31] = rmin1;
    }
}

// ---------- finish: min over 32 splits, add a_sq, global sum --------------
__global__ __launch_bounds__(256) void finish_kernel(
        const float* __restrict__ a_sq, const float* __restrict__ pmin,
        float* __restrict__ out) {
    int r = blockIdx.x * 256 + threadIdx.x;
    float m = pmin[r];
    #pragma unroll
    for (int s = 1; s < TSPLITS; s++)
        m = fminf(m, pmin[(size_t)s * N_PTS + r]);
    float v = a_sq[r] + m;
    #pragma unroll
    for (int k = 1; k < 64; k <<= 1) v += __shfl_xor(v, k);
    __shared__ float red[4];
    if ((threadIdx.x & 63) == 0) red[threadIdx.x >> 6] = v;
    __syncthreads();
    if (threadIdx.x == 0)
        atomicAdd(out, red[0] + red[1] + red[2] + red[3]);
}

extern "C" void kernel_launch(void* const* d_in, const int* in_sizes, int n_in,
                              void* d_out, int out_size, void* d_ws, size_t ws_size,
                              hipStream_t stream) {
    const float* from_pts = (const float*)d_in[0];
    const float* to_pts   = (const float*)d_in[1];
    char* ws = (char*)d_ws;
    float*          a_sq = (float*)ws;                                 //  64 KB
    float*          bsqp = (float*)(ws + (64 << 10));                  //  64 KB
    float*          pmin = (float*)(ws + (128 << 10));                 //   2 MB
    unsigned short* BfF  = (unsigned short*)(ws + (128 << 10) + (2 << 20));           // 2 MB
    unsigned short* AtoF = (unsigned short*)(ws + (128 << 10) + (2 << 20) + (2 << 20)); // 2 MB

    prep_kernel<<<(2 * N_PTS * 8) / 256, 256, 0, stream>>>(
        from_pts, to_pts, a_sq, bsqp, BfF, AtoF, (float*)d_out);
    main_kernel<<<NBLOCKS, 256, 0, stream>>>(BfF, AtoF, bsqp, pmin);
    finish_kernel<<<N_PTS / 256, 256, 0, stream>>>(a_sq, pmin, (float*)d_out);
}

// Round 12
// 91.725 us; speedup vs baseline: 1.5988x; 1.0096x over previous
//
#include <hip/hip_runtime.h>
#include <stdint.h>

// N=M=16384, D=64 fp32. dist[n,m] = a_sq[n] + b_sq[m] - 2 a.b; out = sum_n min_m.
// A(streamed) = TO pts in FRAGMENT order, B(resident) = -2*FROM.
// C[row=to][col=from]: min over rows is IN-LANE (tree16).
// R11 lessons: (1) the harness's 268MB ws-poison fill (~41.6us) is inside the
// timed window -- true kernel budget is dur-45us; (2) LDS staging via
// global_load_lds works (main 49.5 -> ~38us) but one-barrier-per-tile still
// drains a DMA issued only ~300cyc earlier. R12: TWO tiles per stage -->
// half the barriers, 2x the DMA in-flight window (~600+cyc, covers L2
// latency); 2 x 8KB LDS double buffer.
#define N_PTS 16384
#define TSPLITS 32
#define NBLOCKS (256 * TSPLITS / 4)  // 2048 blocks, 4 waves each
#define TO_TILES 16                  // per wave: 512 TO pts = 16 tiles of 32
#define STAGES (TO_TILES / 2)        // 8 stages of 2 tiles

typedef __attribute__((ext_vector_type(8)))  short bf16x8;
typedef __attribute__((ext_vector_type(16))) float f32x16;

__device__ __forceinline__ unsigned short f2bf(float f) {
    unsigned u = __float_as_uint(f);
    u += 0x7FFFu + ((u >> 16) & 1u);   // RNE
    return (unsigned short)(u >> 16);
}
__device__ __forceinline__ float tree16(f32x16 a) {
    float m0 = fminf(fminf(a[0],  a[1]),  a[2]);
    float m1 = fminf(fminf(a[3],  a[4]),  a[5]);
    float m2 = fminf(fminf(a[6],  a[7]),  a[8]);
    float m3 = fminf(fminf(a[9],  a[10]), a[11]);
    float m4 = fminf(fminf(a[12], a[13]), a[14]);
    float m5 = fminf(fminf(a[15], m0), m1);
    return fminf(fminf(fminf(m2, m3), m4), m5);
}

// ---------- prep: fp32 -> bf16 FRAGMENT-ORDER operands + norms ------------
__global__ __launch_bounds__(256) void prep_kernel(
        const float* __restrict__ from_pts, const float* __restrict__ to_pts,
        float* __restrict__ a_sq, float* __restrict__ bsqp,
        unsigned short* __restrict__ BfF, unsigned short* __restrict__ AtoF,
        float* __restrict__ out) {
    int gid = blockIdx.x * 256 + threadIdx.x;   // 0 .. 524287
    int row = gid >> 3;                 // 0..32767 (FROM then TO)
    int sub = gid & 7;
    bool isFrom = row < N_PTS;
    int r = row & (N_PTS - 1);
    const float* src = isFrom ? from_pts : to_pts;
    float4 v0 = ((const float4*)src)[r * 16 + sub * 2];
    float4 v1 = ((const float4*)src)[r * 16 + sub * 2 + 1];
    float s = v0.x*v0.x + v0.y*v0.y + v0.z*v0.z + v0.w*v0.w
            + v1.x*v1.x + v1.y*v1.y + v1.z*v1.z + v1.w*v1.w;
    s += __shfl_xor(s, 1); s += __shfl_xor(s, 2); s += __shfl_xor(s, 4);
    float sc = isFrom ? -2.0f : 1.0f;
    union { unsigned short u[8]; uint4 q; } w;
    w.u[0] = f2bf(v0.x * sc); w.u[1] = f2bf(v0.y * sc);
    w.u[2] = f2bf(v0.z * sc); w.u[3] = f2bf(v0.w * sc);
    w.u[4] = f2bf(v1.x * sc); w.u[5] = f2bf(v1.y * sc);
    w.u[6] = f2bf(v1.z * sc); w.u[7] = f2bf(v1.w * sc);
    int st = r >> 5;                    // subtile / tile index (0..511)
    int m  = r & 31;
    int kb = sub >> 1, h = sub & 1;
    size_t fidx = (((size_t)st * 4 + kb) * 64 + h * 32 + m) * 8;
    if (isFrom) {
        *(uint4*)(BfF + fidx) = w.q;
        if (sub == 0) a_sq[r] = s;
    } else {
        *(uint4*)(AtoF + fidx) = w.q;
        // bsq in C/D-layout order: reg=(m&3)+4*(m>>3), h-half=(m>>2)&1
        if (sub == 0)
            bsqp[st * 32 + ((m >> 2) & 1) * 16 + (m & 3) + 4 * (m >> 3)] = s;
    }
    if (gid == 0) out[0] = 0.0f;
}

// ---------- main: LDS-staged (global_load_lds, 2 tiles/stage) MFMA --------
__global__ __launch_bounds__(256, 4) void main_kernel(
        const unsigned short* __restrict__ BfF,
        const unsigned short* __restrict__ AtoF,
        const float* __restrict__ bsqp, float* __restrict__ pmin) {
    // 2 x 8KB A-stage double buffer (2 tiles/stage) + 2KB cinit chunk
    __shared__ __align__(16) unsigned short abuf[2][4096];
    __shared__ __align__(16) float bsq_s[512];

    const int tid = threadIdx.x;
    const int lane = tid & 63;
    const int l31 = lane & 31;
    const int h   = lane >> 5;
    const int wv  = tid >> 6;           // wave 0..3
    const int wid = (blockIdx.x << 2) + wv;   // 0..8191
    const int fg  = wid & 255;          // 64 FROM pts per wave
    const int ts  = wid >> 8;           // 0..31; block's 4 waves share ts

    const bf16x8* Bv = (const bf16x8*)BfF;

    // stage this block's cinit chunk (512 floats, coalesced) into LDS
    bsq_s[tid]       = bsqp[ts * 512 + tid];
    bsq_s[tid + 256] = bsqp[ts * 512 + 256 + tid];

    // resident FROM fragments: subtiles 2*fg, 2*fg+1 (coalesced loads)
    bf16x8 Bf0[4], Bf1[4];
    #pragma unroll
    for (int kb = 0; kb < 4; kb++) {
        Bf0[kb] = Bv[((size_t)(2 * fg)     * 4 + kb) * 64 + lane];
        Bf1[kb] = Bv[((size_t)(2 * fg + 1) * 4 + kb) * 64 + lane];
    }

    const int gtb = ts * TO_TILES;
    // Stage 2 tiles (8 fragment-blocks of 1KB); wave wv DMAs blocks 2wv,2wv+1.
    // Dest rule: wave-uniform LDS base + lane*16.
    auto stage2 = [&](int s, int buf) {
        #pragma unroll
        for (int j2 = 0; j2 < 2; j2++) {
            int j  = 2 * wv + j2;                    // 0..7
            int gt = gtb + 2 * s + (j >> 2);
            int kb = j & 3;
            const unsigned short* g = AtoF + (((size_t)gt * 4 + kb) * 64 + lane) * 8;
            unsigned short* l = &abuf[buf][j * 512];
            __builtin_amdgcn_global_load_lds(
                (const __attribute__((address_space(1))) unsigned int*)g,
                (__attribute__((address_space(3))) unsigned int*)l, 16, 0, 0);
        }
    };

    float rmin0 = 3.0e38f, rmin1 = 3.0e38f;
    // tl: tile index 0..15; half: which 4KB half of the stage buffer
    auto compute = [&](int tl, int cb, int half) {
        bf16x8 A[4];
        #pragma unroll
        for (int kb = 0; kb < 4; kb++)
            A[kb] = *(const bf16x8*)&abuf[cb][(half * 4 + kb) * 512 + lane * 8];
        union { float4 f[4]; f32x16 v; } cu;
        const float4* cp = (const float4*)&bsq_s[tl * 32 + h * 16];
        cu.f[0] = cp[0]; cu.f[1] = cp[1]; cu.f[2] = cp[2]; cu.f[3] = cp[3];
        f32x16 acc0 = __builtin_amdgcn_mfma_f32_32x32x16_bf16(A[0], Bf0[0], cu.v, 0, 0, 0);
        acc0 = __builtin_amdgcn_mfma_f32_32x32x16_bf16(A[1], Bf0[1], acc0, 0, 0, 0);
        acc0 = __builtin_amdgcn_mfma_f32_32x32x16_bf16(A[2], Bf0[2], acc0, 0, 0, 0);
        acc0 = __builtin_amdgcn_mfma_f32_32x32x16_bf16(A[3], Bf0[3], acc0, 0, 0, 0);
        rmin0 = fminf(rmin0, tree16(acc0));
        f32x16 acc1 = __builtin_amdgcn_mfma_f32_32x32x16_bf16(A[0], Bf1[0], cu.v, 0, 0, 0);
        acc1 = __builtin_amdgcn_mfma_f32_32x32x16_bf16(A[1], Bf1[1], acc1, 0, 0, 0);
        acc1 = __builtin_amdgcn_mfma_f32_32x32x16_bf16(A[2], Bf1[2], acc1, 0, 0, 0);
        acc1 = __builtin_amdgcn_mfma_f32_32x32x16_bf16(A[3], Bf1[3], acc1, 0, 0, 0);
        rmin1 = fminf(rmin1, tree16(acc1));
    };

    stage2(0, 0);
    __syncthreads();                    // drains DMA0 + bsq_s ds_writes
    #pragma unroll 1
    for (int s = 0; s < STAGES - 1; s++) {
        stage2(s + 1, (s + 1) & 1);     // 8KB DMA flies over 16 MFMAs
        compute(2 * s,     s & 1, 0);
        compute(2 * s + 1, s & 1, 1);
        __syncthreads();                // DMA s+1 landed; buf s&1 free
    }
    compute(TO_TILES - 2, (STAGES - 1) & 1, 0);
    compute(TO_TILES - 1, (STAGES - 1) & 1, 1);

    // cross-half min, then plain store: (ts,fg) is wave-unique -> no atomics
    rmin0 = fminf(rmin0, __shfl_xor(rmin0, 32));
    rmin1 = fminf(rmin1, __shfl_xor(rmin1, 32));
    if (lane < 32) {
        pmin[(size_t)ts * N_PTS + fg * 64 + l31]      = rmin0;
        pmin[(size_t)ts * N_PTS + fg * 64 + 32 + l31] = rmin1;
    }
}

// ---------- finish: min over 32 splits, add a_sq, global sum --------------
__global__ __launch_bounds__(256) void finish_kernel(
        const float* __restrict__ a_sq, const float* __restrict__ pmin,
        float* __restrict__ out) {
    int r = blockIdx.x * 256 + threadIdx.x;
    float m = pmin[r];
    #pragma unroll
    for (int s = 1; s < TSPLITS; s++)
        m = fminf(m, pmin[(size_t)s * N_PTS + r]);
    float v = a_sq[r] + m;
    #pragma unroll
    for (int k = 1; k < 64; k <<= 1) v += __shfl_xor(v, k);
    __shared__ float red[4];
    if ((threadIdx.x & 63) == 0) red[threadIdx.x >> 6] = v;
    __syncthreads();
    if (threadIdx.x == 0)
        atomicAdd(out, red[0] + red[1] + red[2] + red[3]);
}

extern "C" void kernel_launch(void* const* d_in, const int* in_sizes, int n_in,
                              void* d_out, int out_size, void* d_ws, size_t ws_size,
                              hipStream_t stream) {
    const float* from_pts = (const float*)d_in[0];
    const float* to_pts   = (const float*)d_in[1];
    char* ws = (char*)d_ws;
    float*          a_sq = (float*)ws;                                 //  64 KB
    float*          bsqp = (float*)(ws + (64 << 10));                  //  64 KB
    float*          pmin = (float*)(ws + (128 << 10));                 //   2 MB
    unsigned short* BfF  = (unsigned short*)(ws + (128 << 10) + (2 << 20));           // 2 MB
    unsigned short* AtoF = (unsigned short*)(ws + (128 << 10) + (2 << 20) + (2 << 20)); // 2 MB

    prep_kernel<<<(2 * N_PTS * 8) / 256, 256, 0, stream>>>(
        from_pts, to_pts, a_sq, bsqp, BfF, AtoF, (float*)d_out);
    main_kernel<<<NBLOCKS, 256, 0, stream>>>(BfF, AtoF, bsqp, pmin);
    finish_kernel<<<N_PTS / 256, 256, 0, stream>>>(a_sq, pmin, (float*)d_out);
}